// Round 1
// 194.949 us; speedup vs baseline: 1.0082x; 1.0082x over previous
//
#include <hip/hip_runtime.h>
#include <math.h>

#define T_LEN 4096   // time length (FFT size)
#define N2    2048   // packed complex FFT size
#define TOPK  7      // int(ln(2047)) = 7
#define NCH   256    // channels (d)
#define R8 0.70710678118654752440    // sqrt(2)/2

// LDS slot map for interleaved complex storage.
// AD(a) = a + (a>>3) + (a>>8): conflict-floor access for every phase pattern
// (strides 256, 32, 4, 1, quad-gather, natural order). Originally tuned for
// 16 B slots; with 8 B float2 slots the residual aliasing is <=2-way (free).
#define AD(a) ((a) + ((a) >> 3) + ((a) >> 8))

// ---------------- K0: fused twiddle table + transpose ------------------------
// blocks [0,16): tw[p] = e^{-2*pi*i*p/4096}, p = 0..4095
// blocks [16, 16+4096): transpose x (b,t,c) -> xt (b,c,t); xt lives in d_out.
__global__ __launch_bounds__(256) void prep_kernel(
    const float* __restrict__ x, float* __restrict__ xt, double2* __restrict__ tw)
{
    if (blockIdx.x < 16) {
        int p = blockIdx.x * 256 + threadIdx.x;
        double th = -2.0 * 3.14159265358979323846 * (double)p / (double)T_LEN;
        tw[p] = make_double2(cos(th), sin(th));
        return;
    }
    __shared__ float tile[64][65];
    const int bid = blockIdx.x - 16;
    const int t0  = (bid & 63) * 64;
    const int c0  = ((bid >> 6) & 3) * 64;
    const int b   = bid >> 8;
    const int tx4 = (threadIdx.x & 15) * 4;
    const int ty  = threadIdx.x >> 4;

    const float* src = x + (size_t)b * T_LEN * NCH;
    for (int r = 0; r < 4; ++r) {
        int t = ty + r * 16;
        float4 v = *(const float4*)(src + (size_t)(t0 + t) * NCH + c0 + tx4);
        tile[t][tx4 + 0] = v.x; tile[t][tx4 + 1] = v.y;
        tile[t][tx4 + 2] = v.z; tile[t][tx4 + 3] = v.w;
    }
    __syncthreads();
    float* dst = xt + (size_t)b * NCH * T_LEN;
    for (int r = 0; r < 4; ++r) {
        int c = ty + r * 16;
        float4 v = make_float4(tile[tx4 + 0][c], tile[tx4 + 1][c],
                               tile[tx4 + 2][c], tile[tx4 + 3][c]);
        *(float4*)(dst + (size_t)(c0 + c) * T_LEN + t0 + tx4) = v;
    }
}

// DIF radix-8 butterfly in registers + twiddle mult by tw[(base*m)&4095]
__device__ __forceinline__ void dft8_tw(double ar[8], double ai[8],
                                        int base, const double2* __restrict__ tw)
{
    double t0r=ar[0]+ar[4], t0i=ai[0]+ai[4], t4r=ar[0]-ar[4], t4i=ai[0]-ai[4];
    double t1r=ar[1]+ar[5], t1i=ai[1]+ai[5], t5r=ar[1]-ar[5], t5i=ai[1]-ai[5];
    double t2r=ar[2]+ar[6], t2i=ai[2]+ai[6], t6r=ar[2]-ar[6], t6i=ai[2]-ai[6];
    double t3r=ar[3]+ar[7], t3i=ai[3]+ai[7], t7r=ar[3]-ar[7], t7i=ai[3]-ai[7];
    double s0r=t0r+t2r, s0i=t0i+t2i, s2r=t0r-t2r, s2i=t0i-t2i;
    double s1r=t1r+t3r, s1i=t1i+t3i, s3r=t1r-t3r, s3i=t1i-t3i;
    ar[0]=s0r+s1r; ai[0]=s0i+s1i;
    ar[4]=s0r-s1r; ai[4]=s0i-s1i;
    ar[2]=s2r+s3i; ai[2]=s2i-s3r;          // s2 - i*s3
    ar[6]=s2r-s3i; ai[6]=s2i+s3r;          // s2 + i*s3
    double c1r=R8*(t5r+t5i), c1i=R8*(t5i-t5r);
    double c2r=t6i,          c2i=-t6r;
    double c3r=R8*(t7i-t7r), c3i=-R8*(t7r+t7i);
    double d0r=t4r+c2r, d0i=t4i+c2i, d1r=t4r-c2r, d1i=t4i-c2i;
    double d2r=c1r+c3r, d2i=c1i+c3i, d3r=c1r-c3r, d3i=c1i-c3i;
    ar[1]=d0r+d2r; ai[1]=d0i+d2i;
    ar[5]=d0r-d2r; ai[5]=d0i-d2i;
    ar[3]=d1r+d3i; ai[3]=d1i-d3r;          // d1 - i*d3
    ar[7]=d1r-d3i; ai[7]=d1i+d3r;          // d1 + i*d3
#pragma unroll
    for (int m = 1; m < 8; ++m) {
        double2 w = tw[(base * m) & 4095];
        double xr = ar[m], xi = ai[m];
        ar[m] = w.x * xr - w.y * xi;
        ai[m] = w.x * xi + w.y * xr;
    }
}

// pack (magnitude^2, bin) into one monotone u64 key: higher mag wins, ties
// (at 2^-41 relative granularity) -> lower k wins. mag >= 0 so IEEE bits
// compare monotonically as unsigned.
__device__ __forceinline__ unsigned long long packkey(double mag, int k) {
    unsigned long long b = __double_as_longlong(mag);
    return (b & ~2047ULL) | (unsigned long long)(2047 - k);
}

// ---------------- K1: register radix-8 real FFT + top-7 ----------------------
// One block per (b,c) column, contiguous in xt. Packed: y_m = x[2m]+i*x[2m+1].
// Butterflies/twiddles/magnitudes in f64 registers; inter-phase storage in
// f32 LDS (halves LDS -> 8 blocks/CU, halves bank traffic; rounding noise
// ~1.5e-7 relative in |X|^2, far below rank-boundary gaps).
// Top-7: per-wave shfl-butterfly top-7 (no barriers) -> 28 candidates ->
// one-wave merge. 7 block barriers total (was 19).
__global__ __launch_bounds__(256, 4) void fft_topk_kernel(
    const float* __restrict__ xt, const double2* __restrict__ tw,
    int* __restrict__ k_out, float4* __restrict__ ab4)
{
    __shared__ float2 zz[AD(N2 - 1) + 3];            // 2312 float2 = 18.5 KB
    __shared__ unsigned long long wavetop[4 * TOPK]; // 28 wave-level candidates
    __shared__ unsigned long long selkey[TOPK];

    const int tid = threadIdx.x;
    const int bc  = blockIdx.x;          // b*256 + c
    const float2* xcol2 = (const float2*)(xt + (size_t)bc * T_LEN);

    double ar[8], ai[8];
    // phase 1: load y[tid + 256u] (coalesced float2), radix-8, tw base 2*tid
#pragma unroll
    for (int u = 0; u < 8; ++u) {
        float2 v = xcol2[tid + (u << 8)];
        ar[u] = (double)v.x; ai[u] = (double)v.y;
    }
    dft8_tw(ar, ai, 2 * tid, tw);
#pragma unroll
    for (int m = 0; m < 8; ++m)
        zz[AD((m << 8) + tid)] = make_float2((float)ar[m], (float)ai[m]);
    __syncthreads();

    // phase 2: sub-FFT size 256, j2 = tid&31, stride 32; tw base 16*j2.
    // Each thread reads and writes ONLY its own 8 slots -> no intra barrier.
    {
        const int g = tid >> 5, j2 = tid & 31, base = (g << 8) + j2;
#pragma unroll
        for (int u = 0; u < 8; ++u) {
            float2 v = zz[AD(base + (u << 5))];
            ar[u] = (double)v.x; ai[u] = (double)v.y;
        }
        dft8_tw(ar, ai, 16 * j2, tw);
#pragma unroll
        for (int m = 0; m < 8; ++m)
            zz[AD(base + (m << 5))] = make_float2((float)ar[m], (float)ai[m]);
    }
    __syncthreads();

    // phase 3: sub-FFT size 32, j3 = tid&3, stride 4; tw base 128*j3.
    {
        const int g3 = tid >> 2, j3 = tid & 3, base = (g3 << 5) + j3;
#pragma unroll
        for (int u = 0; u < 8; ++u) {
            float2 v = zz[AD(base + (u << 2))];
            ar[u] = (double)v.x; ai[u] = (double)v.y;
        }
        dft8_tw(ar, ai, 128 * j3, tw);
#pragma unroll
        for (int m = 0; m < 8; ++m)
            zz[AD(base + (m << 2))] = make_float2((float)ar[m], (float)ai[m]);
    }
    __syncthreads();

    // phase 4: read both stride-1 quads into registers (digit-index space),
    // barrier, DFT4 in registers, write natural-order at AD(k).
#pragma unroll
    for (int q = 0; q < 2; ++q) {
        int h4 = ((q << 8) + tid) << 2;
#pragma unroll
        for (int r = 0; r < 4; ++r) {
            float2 v = zz[AD(h4 + r)];
            ar[q * 4 + r] = (double)v.x; ai[q * 4 + r] = (double)v.y;
        }
    }
    __syncthreads();
#pragma unroll
    for (int q = 0; q < 2; ++q) {
        double b0r = ar[q*4+0], b0i = ai[q*4+0], b1r = ar[q*4+1], b1i = ai[q*4+1];
        double b2r = ar[q*4+2], b2i = ai[q*4+2], b3r = ar[q*4+3], b3i = ai[q*4+3];
        double e0r = b0r + b2r, e0i = b0i + b2i, e1r = b0r - b2r, e1i = b0i - b2i;
        double e2r = b1r + b3r, e2i = b1i + b3i, e3r = b1r - b3r, e3i = b1i - b3i;
        // position p = 4*(q*256+tid)+r  <->  bin k = kbase + r*512
        int kbase = ((tid & 7) << 6) | (((tid >> 3) & 7) << 3) | (q << 2) | (tid >> 6);
        zz[AD(kbase)]        = make_float2((float)(e0r + e2r), (float)(e0i + e2i));
        zz[AD(kbase + 1024)] = make_float2((float)(e0r - e2r), (float)(e0i - e2i));
        zz[AD(kbase +  512)] = make_float2((float)(e1r + e3i), (float)(e1i - e3r)); // e1 - i*e3
        zz[AD(kbase + 1536)] = make_float2((float)(e1r - e3i), (float)(e1i + e3r)); // e1 + i*e3
    }
    __syncthreads();

    // conjugate-pair magnitudes: k in [1,1024]; |X[k]|^2 = |A+WB|^2,
    // |X[2048-k]|^2 = |A-WB|^2 from ONE read pair (Y[k], Y[2048-k]).
    unsigned long long keys[8];
#pragma unroll
    for (int j = 0; j < 4; ++j) {
        int k  = 1 + tid + (j << 8);      // 1..1024
        int kp = N2 - k;                  // 1024..2047
        float2 ykf = zz[AD(k)];
        float2 ypf = zz[AD(kp)];
        double ykx = (double)ykf.x, yky = (double)ykf.y;
        double ypx = (double)ypf.x, ypy = (double)ypf.y;
        double Ar = 0.5 * (ykx + ypx), Ai = 0.5 * (yky - ypy);
        double Br = 0.5 * (yky + ypy), Bi = -0.5 * (ykx - ypx);
        double2 t = tw[k];
        double Cr = t.x * Br - t.y * Bi;
        double Ci = t.x * Bi + t.y * Br;
        double m1 = (Ar + Cr) * (Ar + Cr) + (Ai + Ci) * (Ai + Ci);
        double m2 = (Ar - Cr) * (Ar - Cr) + (Ai - Ci) * (Ai - Ci);
        keys[2 * j]     = packkey(m1, k);
        keys[2 * j + 1] = (kp != k) ? packkey(m2, kp) : 0ULL;
    }

    // ---- top-7, two-level. Keys are unique (bin id in low bits), so the
    // winner of each round lives in exactly one lane; clear is branchless.
    const int wv = tid >> 6, ln = tid & 63;
    unsigned long long lb = 0ULL;
#pragma unroll
    for (int s = 0; s < 8; ++s) lb = (keys[s] > lb) ? keys[s] : lb;

    // level 1: per-wave top-7 via shfl butterflies (no barriers, 4x parallel)
    for (int it = 0; it < TOPK; ++it) {
        unsigned long long v = lb;
#pragma unroll
        for (int off = 32; off; off >>= 1) {
            unsigned long long o = __shfl_xor(v, off);
            if (o > v) v = o;
        }
        if (ln == 0) wavetop[wv * TOPK + it] = v;
#pragma unroll
        for (int s = 0; s < 8; ++s) keys[s] = (keys[s] == v) ? 0ULL : keys[s];
        lb = 0ULL;
#pragma unroll
        for (int s = 0; s < 8; ++s) lb = (keys[s] > lb) ? keys[s] : lb;
    }
    __syncthreads();

    // level 2: merge 28 candidates on one wave (offs <=16 keep lanes <32)
    if (tid < 32) {
        unsigned long long v = (tid < 4 * TOPK) ? wavetop[tid] : 0ULL;
        for (int it = 0; it < TOPK; ++it) {
            unsigned long long m = v;
#pragma unroll
            for (int off = 16; off; off >>= 1) {
                unsigned long long o = __shfl_xor(m, off);
                if (o > m) m = o;
            }
            if (tid == 0) selkey[it] = m;
            if (m == v) v = 0ULL;
        }
    }
    __syncthreads();

    // emit: out = a*cos(theta)+b*sin(theta), theta = 2*pi*k*n/T
    // a = 4*Re/T, b = -4*Im/T (reference double-counts via explicit conjugates)
    // wr + i*wi = e^{+i*2*pi*k/T} for the recon rotator (tw holds e^{-i...}).
    if (tid < TOPK) {
        int k  = 2047 - (int)(selkey[tid] & 2047ULL);
        float2 ykf = zz[AD(k)];
        float2 ypf = zz[AD(N2 - k)];
        double ykx = (double)ykf.x, yky = (double)ykf.y;
        double ypx = (double)ypf.x, ypy = (double)ypf.y;
        double Ar = 0.5 * (ykx + ypx), Ai = 0.5 * (yky - ypy);
        double Br = 0.5 * (yky + ypy), Bi = -0.5 * (ykx - ypx);
        double2 t = tw[k];
        double Xr = Ar + t.x * Br - t.y * Bi;
        double Xi = Ai + t.x * Bi + t.y * Br;
        k_out[tid * 4096 + bc] = k;
        ab4[tid * 4096 + bc] = make_float4(
            (float)( 4.0 * Xr / (double)T_LEN),
            (float)(-4.0 * Xi / (double)T_LEN),
            (float)t.x, (float)(-t.y));
    }
}

// ---------------- K2: reconstruction via per-frequency rotators --------------
// block = 256 threads (one per channel), grid = 16 b * 128 n-chunks of 32.
// Output staged in LDS 16n x 256c subtiles -> contiguous float4 stores.
__global__ __launch_bounds__(256) void recon_kernel(
    const int* __restrict__ k_in, const float4* __restrict__ ab4,
    float* __restrict__ out)
{
    __shared__ float tile[16][256];

    const int tid   = threadIdx.x;        // channel c
    const int chunk = blockIdx.x & 127;
    const int b     = blockIdx.x >> 7;
    const int bc    = (b << 8) + tid;
    const int n0    = chunk << 5;         // 32 time steps per block

    const float c0 = 6.28318530717958647692f / 4096.0f;
    float aa[TOPK], bb[TOPK], zr[TOPK], zi[TOPK], wr[TOPK], wi[TOPK];
#pragma unroll
    for (int j = 0; j < TOPK; ++j) {
        int k    = k_in[j * 4096 + bc];
        float4 v = ab4[j * 4096 + bc];
        aa[j] = v.x; bb[j] = v.y; wr[j] = v.z; wi[j] = v.w;
        int m0 = (k * n0) & (T_LEN - 1);      // exact integer phase reduction
        float ang = (float)m0 * c0;
        zr[j] = __cosf(ang);
        zi[j] = __sinf(ang);
    }

    float* obase = out + ((size_t)b * T_LEN + n0) * NCH;
    for (int r = 0; r < 2; ++r) {             // 2 subtiles of 16 n
#pragma unroll
        for (int i = 0; i < 16; ++i) {
            float acc = 0.f;
#pragma unroll
            for (int j = 0; j < TOPK; ++j) {
                acc += aa[j] * zr[j] + bb[j] * zi[j];
                float nzr = zr[j] * wr[j] - zi[j] * wi[j];
                zi[j] = zr[j] * wi[j] + zi[j] * wr[j];
                zr[j] = nzr;
            }
            tile[i][tid] = acc;
        }
        __syncthreads();
        // 1024 float4s per subtile, 4 per thread, contiguous per wave
#pragma unroll
        for (int s = 0; s < 4; ++s) {
            int fid = tid + (s << 8);
            int ni  = fid >> 6;
            int c4  = (fid & 63) << 2;
            float4 v = make_float4(tile[ni][c4], tile[ni][c4 + 1],
                                   tile[ni][c4 + 2], tile[ni][c4 + 3]);
            *(float4*)(obase + (size_t)((r << 4) + ni) * NCH + c4) = v;
        }
        __syncthreads();
    }
}

// ---------------- launch -----------------------------------------------------
extern "C" void kernel_launch(void* const* d_in, const int* in_sizes, int n_in,
                              void* d_out, int out_size, void* d_ws, size_t ws_size,
                              hipStream_t stream) {
    const float* x   = (const float*)d_in[0];
    float*       out = (float*)d_out;
    char*        ws  = (char*)d_ws;

    // ws layout: [0, 65536)            twiddles double2[4096]
    //            [65536, +114688)      k int[7][4096]
    //            [180224, +458752)     ab4 float4[7][4096]
    double2* tw   = (double2*)(ws);
    int*     k_ws = (int*)   (ws + 65536);
    float4*  ab_ws= (float4*)(ws + 180224);

    // d_out doubles as the transposed-x scratch (exactly 64 MB); recon_kernel
    // overwrites every element of it last, so validation sees only the output.
    prep_kernel     <<<16 + 4096, 256, 0, stream>>>(x, out, tw);
    fft_topk_kernel <<<4096, 256, 0, stream>>>(out, tw, k_ws, ab_ws);
    recon_kernel    <<<2048, 256, 0, stream>>>(k_ws, ab_ws, out);
}

// Round 2
// 186.765 us; speedup vs baseline: 1.0524x; 1.0438x over previous
//
#include <hip/hip_runtime.h>
#include <math.h>

#define T_LEN 4096   // time length (FFT size)
#define N2    2048   // packed complex FFT size
#define TOPK  7      // int(ln(2047)) = 7
#define NCH   256    // channels (d)
#define R8F 0.70710678f              // sqrt(2)/2 in f32

// LDS slot map for interleaved complex storage.
// AD(a) = a + (a>>3) + (a>>8): conflict-floor access for every phase pattern
// (strides 256, 32, 4, 1, quad-gather, natural order).
#define AD(a) ((a) + ((a) >> 3) + ((a) >> 8))

// ---------------- K0: fused twiddle tables + transpose -----------------------
// blocks [0,16): tw[p] = e^{-2*pi*i*p/4096} (f64) and twf[p] (f32), p=0..4095
// blocks [16, 16+4096): transpose x (b,t,c) -> xt (b,c,t); xt lives in d_out.
__global__ __launch_bounds__(256) void prep_kernel(
    const float* __restrict__ x, float* __restrict__ xt,
    double2* __restrict__ tw, float2* __restrict__ twf)
{
    if (blockIdx.x < 16) {
        int p = blockIdx.x * 256 + threadIdx.x;
        double th = -2.0 * 3.14159265358979323846 * (double)p / (double)T_LEN;
        double c = cos(th), s = sin(th);
        tw[p]  = make_double2(c, s);
        twf[p] = make_float2((float)c, (float)s);
        return;
    }
    __shared__ float tile[64][65];
    const int bid = blockIdx.x - 16;
    const int t0  = (bid & 63) * 64;
    const int c0  = ((bid >> 6) & 3) * 64;
    const int b   = bid >> 8;
    const int tx4 = (threadIdx.x & 15) * 4;
    const int ty  = threadIdx.x >> 4;

    const float* src = x + (size_t)b * T_LEN * NCH;
    for (int r = 0; r < 4; ++r) {
        int t = ty + r * 16;
        float4 v = *(const float4*)(src + (size_t)(t0 + t) * NCH + c0 + tx4);
        tile[t][tx4 + 0] = v.x; tile[t][tx4 + 1] = v.y;
        tile[t][tx4 + 2] = v.z; tile[t][tx4 + 3] = v.w;
    }
    __syncthreads();
    float* dst = xt + (size_t)b * NCH * T_LEN;
    for (int r = 0; r < 4; ++r) {
        int c = ty + r * 16;
        float4 v = make_float4(tile[tx4 + 0][c], tile[tx4 + 1][c],
                               tile[tx4 + 2][c], tile[tx4 + 3][c]);
        *(float4*)(dst + (size_t)(c0 + c) * T_LEN + t0 + tx4) = v;
    }
}

// DIF radix-8 butterfly in f32 registers + twiddle mult by twf[(base*m)&4095]
__device__ __forceinline__ void dft8_twf(float ar[8], float ai[8],
                                         int base, const float2* __restrict__ twf)
{
    float t0r=ar[0]+ar[4], t0i=ai[0]+ai[4], t4r=ar[0]-ar[4], t4i=ai[0]-ai[4];
    float t1r=ar[1]+ar[5], t1i=ai[1]+ai[5], t5r=ar[1]-ar[5], t5i=ai[1]-ai[5];
    float t2r=ar[2]+ar[6], t2i=ai[2]+ai[6], t6r=ar[2]-ar[6], t6i=ai[2]-ai[6];
    float t3r=ar[3]+ar[7], t3i=ai[3]+ai[7], t7r=ar[3]-ar[7], t7i=ai[3]-ai[7];
    float s0r=t0r+t2r, s0i=t0i+t2i, s2r=t0r-t2r, s2i=t0i-t2i;
    float s1r=t1r+t3r, s1i=t1i+t3i, s3r=t1r-t3r, s3i=t1i-t3i;
    ar[0]=s0r+s1r; ai[0]=s0i+s1i;
    ar[4]=s0r-s1r; ai[4]=s0i-s1i;
    ar[2]=s2r+s3i; ai[2]=s2i-s3r;          // s2 - i*s3
    ar[6]=s2r-s3i; ai[6]=s2i+s3r;          // s2 + i*s3
    float c1r=R8F*(t5r+t5i), c1i=R8F*(t5i-t5r);
    float c2r=t6i,           c2i=-t6r;
    float c3r=R8F*(t7i-t7r), c3i=-R8F*(t7r+t7i);
    float d0r=t4r+c2r, d0i=t4i+c2i, d1r=t4r-c2r, d1i=t4i-c2i;
    float d2r=c1r+c3r, d2i=c1i+c3i, d3r=c1r-c3r, d3i=c1i-c3i;
    ar[1]=d0r+d2r; ai[1]=d0i+d2i;
    ar[5]=d0r-d2r; ai[5]=d0i-d2i;
    ar[3]=d1r+d3i; ai[3]=d1i-d3r;          // d1 - i*d3
    ar[7]=d1r-d3i; ai[7]=d1i+d3r;          // d1 + i*d3
#pragma unroll
    for (int m = 1; m < 8; ++m) {
        float2 w = twf[(base * m) & 4095];
        float xr = ar[m], xi = ai[m];
        ar[m] = w.x * xr - w.y * xi;
        ai[m] = w.x * xi + w.y * xr;
    }
}

// pack (f32 magnitude^2 bits, bin) into one monotone u64 key: higher mag wins;
// exact f32 ties -> lower k wins. mag >= 0 so IEEE bits compare monotonically
// as unsigned. Full f32 precision preserved (no mantissa truncation).
__device__ __forceinline__ unsigned long long packkey32(float mag, int k) {
    return ((unsigned long long)__float_as_uint(mag) << 32)
         | (unsigned long long)(2047 - k);
}

// ---------------- K1: register radix-8 real FFT (f32) + top-7 ----------------
// One block per (b,c) column, contiguous in xt. Packed: y_m = x[2m]+i*x[2m+1].
// Whole pipeline in f32 (reference itself is complex64): halves VALU issue
// (f32 = 2 cyc/instr vs f64 = 4) and removes all f32<->f64 converts at the
// LDS boundary. Final coefficient emit (7 lanes) still f64 from the f64 table.
// Top-7: per-wave shfl-butterfly top-7 (no barriers) -> 28 candidates ->
// one-wave merge. 7 block barriers total.
__global__ __launch_bounds__(256, 8) void fft_topk_kernel(
    const float* __restrict__ xt, const double2* __restrict__ tw,
    const float2* __restrict__ twf,
    int* __restrict__ k_out, float4* __restrict__ ab4)
{
    __shared__ float2 zz[AD(N2 - 1) + 3];            // 2312 float2 = 18.5 KB
    __shared__ unsigned long long wavetop[4 * TOPK]; // 28 wave-level candidates
    __shared__ unsigned long long selkey[TOPK];

    const int tid = threadIdx.x;
    const int bc  = blockIdx.x;          // b*256 + c
    const float2* xcol2 = (const float2*)(xt + (size_t)bc * T_LEN);

    float ar[8], ai[8];
    // phase 1: load y[tid + 256u] (coalesced float2), radix-8, tw base 2*tid
#pragma unroll
    for (int u = 0; u < 8; ++u) {
        float2 v = xcol2[tid + (u << 8)];
        ar[u] = v.x; ai[u] = v.y;
    }
    dft8_twf(ar, ai, 2 * tid, twf);
#pragma unroll
    for (int m = 0; m < 8; ++m)
        zz[AD((m << 8) + tid)] = make_float2(ar[m], ai[m]);
    __syncthreads();

    // phase 2: sub-FFT size 256, j2 = tid&31, stride 32; tw base 16*j2.
    // Each thread reads and writes ONLY its own 8 slots -> no intra barrier.
    {
        const int g = tid >> 5, j2 = tid & 31, base = (g << 8) + j2;
#pragma unroll
        for (int u = 0; u < 8; ++u) {
            float2 v = zz[AD(base + (u << 5))];
            ar[u] = v.x; ai[u] = v.y;
        }
        dft8_twf(ar, ai, 16 * j2, twf);
#pragma unroll
        for (int m = 0; m < 8; ++m)
            zz[AD(base + (m << 5))] = make_float2(ar[m], ai[m]);
    }
    __syncthreads();

    // phase 3: sub-FFT size 32, j3 = tid&3, stride 4; tw base 128*j3.
    {
        const int g3 = tid >> 2, j3 = tid & 3, base = (g3 << 5) + j3;
#pragma unroll
        for (int u = 0; u < 8; ++u) {
            float2 v = zz[AD(base + (u << 2))];
            ar[u] = v.x; ai[u] = v.y;
        }
        dft8_twf(ar, ai, 128 * j3, twf);
#pragma unroll
        for (int m = 0; m < 8; ++m)
            zz[AD(base + (m << 2))] = make_float2(ar[m], ai[m]);
    }
    __syncthreads();

    // phase 4: read both stride-1 quads into registers (digit-index space),
    // barrier, DFT4 in registers, write natural-order at AD(k).
#pragma unroll
    for (int q = 0; q < 2; ++q) {
        int h4 = ((q << 8) + tid) << 2;
#pragma unroll
        for (int r = 0; r < 4; ++r) {
            float2 v = zz[AD(h4 + r)];
            ar[q * 4 + r] = v.x; ai[q * 4 + r] = v.y;
        }
    }
    __syncthreads();
#pragma unroll
    for (int q = 0; q < 2; ++q) {
        float b0r = ar[q*4+0], b0i = ai[q*4+0], b1r = ar[q*4+1], b1i = ai[q*4+1];
        float b2r = ar[q*4+2], b2i = ai[q*4+2], b3r = ar[q*4+3], b3i = ai[q*4+3];
        float e0r = b0r + b2r, e0i = b0i + b2i, e1r = b0r - b2r, e1i = b0i - b2i;
        float e2r = b1r + b3r, e2i = b1i + b3i, e3r = b1r - b3r, e3i = b1i - b3i;
        // position p = 4*(q*256+tid)+r  <->  bin k = kbase + r*512
        int kbase = ((tid & 7) << 6) | (((tid >> 3) & 7) << 3) | (q << 2) | (tid >> 6);
        zz[AD(kbase)]        = make_float2(e0r + e2r, e0i + e2i);
        zz[AD(kbase + 1024)] = make_float2(e0r - e2r, e0i - e2i);
        zz[AD(kbase +  512)] = make_float2(e1r + e3i, e1i - e3r);  // e1 - i*e3
        zz[AD(kbase + 1536)] = make_float2(e1r - e3i, e1i + e3r);  // e1 + i*e3
    }
    __syncthreads();

    // conjugate-pair magnitudes: k in [1,1024]; |X[k]|^2 = |A+WB|^2,
    // |X[2048-k]|^2 = |A-WB|^2 from ONE read pair (Y[k], Y[2048-k]).
    unsigned long long keys[8];
#pragma unroll
    for (int j = 0; j < 4; ++j) {
        int k  = 1 + tid + (j << 8);      // 1..1024
        int kp = N2 - k;                  // 1024..2047
        float2 yk = zz[AD(k)];
        float2 yp = zz[AD(kp)];
        float Ar = 0.5f * (yk.x + yp.x), Ai = 0.5f * (yk.y - yp.y);
        float Br = 0.5f * (yk.y + yp.y), Bi = -0.5f * (yk.x - yp.x);
        float2 t = twf[k];
        float Cr = t.x * Br - t.y * Bi;
        float Ci = t.x * Bi + t.y * Br;
        float m1 = (Ar + Cr) * (Ar + Cr) + (Ai + Ci) * (Ai + Ci);
        float m2 = (Ar - Cr) * (Ar - Cr) + (Ai - Ci) * (Ai - Ci);
        keys[2 * j]     = packkey32(m1, k);
        keys[2 * j + 1] = (kp != k) ? packkey32(m2, kp) : 0ULL;
    }

    // ---- top-7, two-level. Keys are unique (bin id in low bits), so the
    // winner of each round lives in exactly one lane; clear is branchless.
    const int wv = tid >> 6, ln = tid & 63;
    unsigned long long lb = 0ULL;
#pragma unroll
    for (int s = 0; s < 8; ++s) lb = (keys[s] > lb) ? keys[s] : lb;

    // level 1: per-wave top-7 via shfl butterflies (no barriers, 4x parallel)
    for (int it = 0; it < TOPK; ++it) {
        unsigned long long v = lb;
#pragma unroll
        for (int off = 32; off; off >>= 1) {
            unsigned long long o = __shfl_xor(v, off);
            if (o > v) v = o;
        }
        if (ln == 0) wavetop[wv * TOPK + it] = v;
#pragma unroll
        for (int s = 0; s < 8; ++s) keys[s] = (keys[s] == v) ? 0ULL : keys[s];
        lb = 0ULL;
#pragma unroll
        for (int s = 0; s < 8; ++s) lb = (keys[s] > lb) ? keys[s] : lb;
    }
    __syncthreads();

    // level 2: merge 28 candidates on one wave (offs <=16 keep lanes <32)
    if (tid < 32) {
        unsigned long long v = (tid < 4 * TOPK) ? wavetop[tid] : 0ULL;
        for (int it = 0; it < TOPK; ++it) {
            unsigned long long m = v;
#pragma unroll
            for (int off = 16; off; off >>= 1) {
                unsigned long long o = __shfl_xor(m, off);
                if (o > m) m = o;
            }
            if (tid == 0) selkey[it] = m;
            if (m == v) v = 0ULL;
        }
    }
    __syncthreads();

    // emit: out = a*cos(theta)+b*sin(theta), theta = 2*pi*k*n/T
    // a = 4*Re/T, b = -4*Im/T (reference double-counts via explicit conjugates)
    // wr + i*wi = e^{+i*2*pi*k/T} for the recon rotator (tw holds e^{-i...}).
    if (tid < TOPK) {
        int k  = 2047 - (int)(selkey[tid] & 2047ULL);
        float2 ykf = zz[AD(k)];
        float2 ypf = zz[AD(N2 - k)];
        double ykx = (double)ykf.x, yky = (double)ykf.y;
        double ypx = (double)ypf.x, ypy = (double)ypf.y;
        double Ar = 0.5 * (ykx + ypx), Ai = 0.5 * (yky - ypy);
        double Br = 0.5 * (yky + ypy), Bi = -0.5 * (ykx - ypx);
        double2 t = tw[k];
        double Xr = Ar + t.x * Br - t.y * Bi;
        double Xi = Ai + t.x * Bi + t.y * Br;
        k_out[tid * 4096 + bc] = k;
        ab4[tid * 4096 + bc] = make_float4(
            (float)( 4.0 * Xr / (double)T_LEN),
            (float)(-4.0 * Xi / (double)T_LEN),
            (float)t.x, (float)(-t.y));
    }
}

// ---------------- K2: reconstruction via per-frequency rotators --------------
// block = 256 threads (one per channel), grid = 16 b * 128 n-chunks of 32.
// Output staged in LDS 16n x 256c subtiles -> contiguous float4 stores.
__global__ __launch_bounds__(256) void recon_kernel(
    const int* __restrict__ k_in, const float4* __restrict__ ab4,
    float* __restrict__ out)
{
    __shared__ float tile[16][256];

    const int tid   = threadIdx.x;        // channel c
    const int chunk = blockIdx.x & 127;
    const int b     = blockIdx.x >> 7;
    const int bc    = (b << 8) + tid;
    const int n0    = chunk << 5;         // 32 time steps per block

    const float c0 = 6.28318530717958647692f / 4096.0f;
    float aa[TOPK], bb[TOPK], zr[TOPK], zi[TOPK], wr[TOPK], wi[TOPK];
#pragma unroll
    for (int j = 0; j < TOPK; ++j) {
        int k    = k_in[j * 4096 + bc];
        float4 v = ab4[j * 4096 + bc];
        aa[j] = v.x; bb[j] = v.y; wr[j] = v.z; wi[j] = v.w;
        int m0 = (k * n0) & (T_LEN - 1);      // exact integer phase reduction
        float ang = (float)m0 * c0;
        zr[j] = __cosf(ang);
        zi[j] = __sinf(ang);
    }

    float* obase = out + ((size_t)b * T_LEN + n0) * NCH;
    for (int r = 0; r < 2; ++r) {             // 2 subtiles of 16 n
#pragma unroll
        for (int i = 0; i < 16; ++i) {
            float acc = 0.f;
#pragma unroll
            for (int j = 0; j < TOPK; ++j) {
                acc += aa[j] * zr[j] + bb[j] * zi[j];
                float nzr = zr[j] * wr[j] - zi[j] * wi[j];
                zi[j] = zr[j] * wi[j] + zi[j] * wr[j];
                zr[j] = nzr;
            }
            tile[i][tid] = acc;
        }
        __syncthreads();
        // 1024 float4s per subtile, 4 per thread, contiguous per wave
#pragma unroll
        for (int s = 0; s < 4; ++s) {
            int fid = tid + (s << 8);
            int ni  = fid >> 6;
            int c4  = (fid & 63) << 2;
            float4 v = make_float4(tile[ni][c4], tile[ni][c4 + 1],
                                   tile[ni][c4 + 2], tile[ni][c4 + 3]);
            *(float4*)(obase + (size_t)((r << 4) + ni) * NCH + c4) = v;
        }
        __syncthreads();
    }
}

// ---------------- launch -----------------------------------------------------
extern "C" void kernel_launch(void* const* d_in, const int* in_sizes, int n_in,
                              void* d_out, int out_size, void* d_ws, size_t ws_size,
                              hipStream_t stream) {
    const float* x   = (const float*)d_in[0];
    float*       out = (float*)d_out;
    char*        ws  = (char*)d_ws;

    // ws layout: [0, 65536)            tw   double2[4096]
    //            [65536, +114688)      k    int[7][4096]
    //            [180224, +458752)     ab4  float4[7][4096]
    //            [638976, +32768)      twf  float2[4096]
    double2* tw    = (double2*)(ws);
    int*     k_ws  = (int*)   (ws + 65536);
    float4*  ab_ws = (float4*)(ws + 180224);
    float2*  twf   = (float2*)(ws + 638976);

    // d_out doubles as the transposed-x scratch (exactly 64 MB); recon_kernel
    // overwrites every element of it last, so validation sees only the output.
    prep_kernel     <<<16 + 4096, 256, 0, stream>>>(x, out, tw, twf);
    fft_topk_kernel <<<4096, 256, 0, stream>>>(out, tw, twf, k_ws, ab_ws);
    recon_kernel    <<<2048, 256, 0, stream>>>(k_ws, ab_ws, out);
}

// Round 3
// 181.584 us; speedup vs baseline: 1.0824x; 1.0285x over previous
//
#include <hip/hip_runtime.h>
#include <math.h>

#define T_LEN 4096   // time length (FFT size)
#define N2    2048   // packed complex FFT size
#define TOPK  7      // int(ln(2047)) = 7
#define NCH   256    // channels (d)
#define R8F 0.70710678f              // sqrt(2)/2 in f32

// LDS slot map for interleaved complex storage.
// AD(a) = a + (a>>3) + (a>>8): conflict-floor access for every phase pattern
// (strides 256, 32, 4, 1, quad-gather, natural order).
#define AD(a) ((a) + ((a) >> 3) + ((a) >> 8))

// ---------------- K0: fused twiddle tables + transpose -----------------------
// blocks [0,16): tw[p] = e^{-2*pi*i*p/4096} (f64) and twf[p] (f32), p=0..4095
// blocks [16, 16+4096): transpose x (b,t,c) -> xt (b,c,t); xt lives in d_out.
__global__ __launch_bounds__(256) void prep_kernel(
    const float* __restrict__ x, float* __restrict__ xt,
    double2* __restrict__ tw, float2* __restrict__ twf)
{
    if (blockIdx.x < 16) {
        int p = blockIdx.x * 256 + threadIdx.x;
        double th = -2.0 * 3.14159265358979323846 * (double)p / (double)T_LEN;
        double c = cos(th), s = sin(th);
        tw[p]  = make_double2(c, s);
        twf[p] = make_float2((float)c, (float)s);
        return;
    }
    __shared__ float tile[64][65];
    const int bid = blockIdx.x - 16;
    const int t0  = (bid & 63) * 64;
    const int c0  = ((bid >> 6) & 3) * 64;
    const int b   = bid >> 8;
    const int tx4 = (threadIdx.x & 15) * 4;
    const int ty  = threadIdx.x >> 4;

    const float* src = x + (size_t)b * T_LEN * NCH;
    for (int r = 0; r < 4; ++r) {
        int t = ty + r * 16;
        float4 v = *(const float4*)(src + (size_t)(t0 + t) * NCH + c0 + tx4);
        tile[t][tx4 + 0] = v.x; tile[t][tx4 + 1] = v.y;
        tile[t][tx4 + 2] = v.z; tile[t][tx4 + 3] = v.w;
    }
    __syncthreads();
    float* dst = xt + (size_t)b * NCH * T_LEN;
    for (int r = 0; r < 4; ++r) {
        int c = ty + r * 16;
        float4 v = make_float4(tile[tx4 + 0][c], tile[tx4 + 1][c],
                               tile[tx4 + 2][c], tile[tx4 + 3][c]);
        *(float4*)(dst + (size_t)(c0 + c) * T_LEN + t0 + tx4) = v;
    }
}

__device__ __forceinline__ void cmulf(float& xr, float& xi, float wrr, float wii) {
    float r = wrr * xr - wii * xi;
    xi = wrr * xi + wii * xr;
    xr = r;
}

// DIF radix-8 butterfly in f32 registers. Twiddles generated in-register as
// powers of w1 = e^{-2*pi*i*base/4096} (ONE 8 B load per call instead of 7
// lane-scattered loads -> removes ~400 L1 request cycles per wave per call).
// Power error <= ~5 ulp: selection gaps are >=1e-4 relative (f64->f32 switch
// left absmax bit-identical), so rank order is unaffected.
__device__ __forceinline__ void dft8_pw(float ar[8], float ai[8],
                                        float w1r, float w1i)
{
    float t0r=ar[0]+ar[4], t0i=ai[0]+ai[4], t4r=ar[0]-ar[4], t4i=ai[0]-ai[4];
    float t1r=ar[1]+ar[5], t1i=ai[1]+ai[5], t5r=ar[1]-ar[5], t5i=ai[1]-ai[5];
    float t2r=ar[2]+ar[6], t2i=ai[2]+ai[6], t6r=ar[2]-ar[6], t6i=ai[2]-ai[6];
    float t3r=ar[3]+ar[7], t3i=ai[3]+ai[7], t7r=ar[3]-ar[7], t7i=ai[3]-ai[7];
    float s0r=t0r+t2r, s0i=t0i+t2i, s2r=t0r-t2r, s2i=t0i-t2i;
    float s1r=t1r+t3r, s1i=t1i+t3i, s3r=t1r-t3r, s3i=t1i-t3i;
    ar[0]=s0r+s1r; ai[0]=s0i+s1i;
    ar[4]=s0r-s1r; ai[4]=s0i-s1i;
    ar[2]=s2r+s3i; ai[2]=s2i-s3r;          // s2 - i*s3
    ar[6]=s2r-s3i; ai[6]=s2i+s3r;          // s2 + i*s3
    float c1r=R8F*(t5r+t5i), c1i=R8F*(t5i-t5r);
    float c2r=t6i,           c2i=-t6r;
    float c3r=R8F*(t7i-t7r), c3i=-R8F*(t7r+t7i);
    float d0r=t4r+c2r, d0i=t4i+c2i, d1r=t4r-c2r, d1i=t4i-c2i;
    float d2r=c1r+c3r, d2i=c1i+c3i, d3r=c1r-c3r, d3i=c1i-c3i;
    ar[1]=d0r+d2r; ai[1]=d0i+d2i;
    ar[5]=d0r-d2r; ai[5]=d0i-d2i;
    ar[3]=d1r+d3i; ai[3]=d1i-d3r;          // d1 - i*d3
    ar[7]=d1r-d3i; ai[7]=d1i+d3r;          // d1 + i*d3

    float w2r = w1r*w1r - w1i*w1i, w2i = 2.0f*w1r*w1i;
    float w3r = w2r*w1r - w2i*w1i, w3i = w2r*w1i + w2i*w1r;
    float w4r = w2r*w2r - w2i*w2i, w4i = 2.0f*w2r*w2i;
    float w5r = w3r*w2r - w3i*w2i, w5i = w3r*w2i + w3i*w2r;
    float w6r = w3r*w3r - w3i*w3i, w6i = 2.0f*w3r*w3i;
    float w7r = w4r*w3r - w4i*w3i, w7i = w4r*w3i + w4i*w3r;
    cmulf(ar[1], ai[1], w1r, w1i);
    cmulf(ar[2], ai[2], w2r, w2i);
    cmulf(ar[3], ai[3], w3r, w3i);
    cmulf(ar[4], ai[4], w4r, w4i);
    cmulf(ar[5], ai[5], w5r, w5i);
    cmulf(ar[6], ai[6], w6r, w6i);
    cmulf(ar[7], ai[7], w7r, w7i);
}

// pack (f32 magnitude^2 bits, bin) into one monotone u64 key: higher mag wins;
// exact f32 ties -> lower k wins. mag >= 0 so IEEE bits compare monotonically
// as unsigned. Full f32 precision preserved (no mantissa truncation).
__device__ __forceinline__ unsigned long long packkey32(float mag, int k) {
    return ((unsigned long long)__float_as_uint(mag) << 32)
         | (unsigned long long)(2047 - k);
}

// descending compare-swap for the per-thread sorting network
#define CSWAP(i, j) { unsigned long long a_ = keys[i], b_ = keys[j]; \
                      keys[i] = a_ > b_ ? a_ : b_; keys[j] = a_ > b_ ? b_ : a_; }

// ---------------- K1: register radix-8 real FFT (f32) + top-7 ----------------
// One block per (b,c) column, contiguous in xt. Packed: y_m = x[2m]+i*x[2m+1].
// Top-7: per-thread 8-key sort (Batcher net, 19 comparators) -> per-wave
// shfl-butterfly rounds exposing only each thread's current head (winner does
// a 1-lane shift-down) -> 28 candidates -> one-wave merge.
__global__ __launch_bounds__(256, 8) void fft_topk_kernel(
    const float* __restrict__ xt, const double2* __restrict__ tw,
    const float2* __restrict__ twf,
    int* __restrict__ k_out, float4* __restrict__ ab4)
{
    __shared__ float2 zz[AD(N2 - 1) + 3];            // 2312 float2 = 18.5 KB
    __shared__ unsigned long long wavetop[4 * TOPK]; // 28 wave-level candidates
    __shared__ unsigned long long selkey[TOPK];

    const int tid = threadIdx.x;
    const int bc  = blockIdx.x;          // b*256 + c
    const float2* xcol2 = (const float2*)(xt + (size_t)bc * T_LEN);

    float ar[8], ai[8];
    // phase 1: load y[tid + 256u] (coalesced float2), radix-8, tw base 2*tid
#pragma unroll
    for (int u = 0; u < 8; ++u) {
        float2 v = xcol2[tid + (u << 8)];
        ar[u] = v.x; ai[u] = v.y;
    }
    {
        float2 w1 = twf[2 * tid];            // lane-stride 16 B: coalesced-ish
        dft8_pw(ar, ai, w1.x, w1.y);
    }
#pragma unroll
    for (int m = 0; m < 8; ++m)
        zz[AD((m << 8) + tid)] = make_float2(ar[m], ai[m]);
    __syncthreads();

    // phase 2: sub-FFT size 256, j2 = tid&31, stride 32; tw base 16*j2.
    // Each thread reads and writes ONLY its own 8 slots -> no intra barrier.
    {
        const int g = tid >> 5, j2 = tid & 31, base = (g << 8) + j2;
#pragma unroll
        for (int u = 0; u < 8; ++u) {
            float2 v = zz[AD(base + (u << 5))];
            ar[u] = v.x; ai[u] = v.y;
        }
        float2 w1 = twf[16 * j2];
        dft8_pw(ar, ai, w1.x, w1.y);
#pragma unroll
        for (int m = 0; m < 8; ++m)
            zz[AD(base + (m << 5))] = make_float2(ar[m], ai[m]);
    }
    __syncthreads();

    // phase 3: sub-FFT size 32, j3 = tid&3, stride 4; tw base 128*j3.
    {
        const int g3 = tid >> 2, j3 = tid & 3, base = (g3 << 5) + j3;
#pragma unroll
        for (int u = 0; u < 8; ++u) {
            float2 v = zz[AD(base + (u << 2))];
            ar[u] = v.x; ai[u] = v.y;
        }
        float2 w1 = twf[128 * j3];           // 4 distinct addrs: broadcast
        dft8_pw(ar, ai, w1.x, w1.y);
#pragma unroll
        for (int m = 0; m < 8; ++m)
            zz[AD(base + (m << 2))] = make_float2(ar[m], ai[m]);
    }
    __syncthreads();

    // phase 4: read both stride-1 quads into registers (digit-index space),
    // barrier, DFT4 in registers, write natural-order at AD(k).
#pragma unroll
    for (int q = 0; q < 2; ++q) {
        int h4 = ((q << 8) + tid) << 2;
#pragma unroll
        for (int r = 0; r < 4; ++r) {
            float2 v = zz[AD(h4 + r)];
            ar[q * 4 + r] = v.x; ai[q * 4 + r] = v.y;
        }
    }
    __syncthreads();
#pragma unroll
    for (int q = 0; q < 2; ++q) {
        float b0r = ar[q*4+0], b0i = ai[q*4+0], b1r = ar[q*4+1], b1i = ai[q*4+1];
        float b2r = ar[q*4+2], b2i = ai[q*4+2], b3r = ar[q*4+3], b3i = ai[q*4+3];
        float e0r = b0r + b2r, e0i = b0i + b2i, e1r = b0r - b2r, e1i = b0i - b2i;
        float e2r = b1r + b3r, e2i = b1i + b3i, e3r = b1r - b3r, e3i = b1i - b3i;
        // position p = 4*(q*256+tid)+r  <->  bin k = kbase + r*512
        int kbase = ((tid & 7) << 6) | (((tid >> 3) & 7) << 3) | (q << 2) | (tid >> 6);
        zz[AD(kbase)]        = make_float2(e0r + e2r, e0i + e2i);
        zz[AD(kbase + 1024)] = make_float2(e0r - e2r, e0i - e2i);
        zz[AD(kbase +  512)] = make_float2(e1r + e3i, e1i - e3r);  // e1 - i*e3
        zz[AD(kbase + 1536)] = make_float2(e1r - e3i, e1i + e3r);  // e1 + i*e3
    }
    __syncthreads();

    // conjugate-pair magnitudes: k in [1,1024]; |X[k]|^2 = |A+WB|^2,
    // |X[2048-k]|^2 = |A-WB|^2 from ONE read pair (Y[k], Y[2048-k]).
    unsigned long long keys[8];
#pragma unroll
    for (int j = 0; j < 4; ++j) {
        int k  = 1 + tid + (j << 8);      // 1..1024
        int kp = N2 - k;                  // 1024..2047
        float2 yk = zz[AD(k)];
        float2 yp = zz[AD(kp)];
        float Ar = 0.5f * (yk.x + yp.x), Ai = 0.5f * (yk.y - yp.y);
        float Br = 0.5f * (yk.y + yp.y), Bi = -0.5f * (yk.x - yp.x);
        float2 t = twf[k];                // lane-stride 8 B: coalesced
        float Cr = t.x * Br - t.y * Bi;
        float Ci = t.x * Bi + t.y * Br;
        float m1 = (Ar + Cr) * (Ar + Cr) + (Ai + Ci) * (Ai + Ci);
        float m2 = (Ar - Cr) * (Ar - Cr) + (Ai - Ci) * (Ai - Ci);
        keys[2 * j]     = packkey32(m1, k);
        keys[2 * j + 1] = (kp != k) ? packkey32(m2, kp) : 0ULL;
    }

    // ---- per-thread descending sort (Batcher 8-element network, 19 CEs)
    CSWAP(0,1) CSWAP(2,3) CSWAP(4,5) CSWAP(6,7)
    CSWAP(0,2) CSWAP(1,3) CSWAP(4,6) CSWAP(5,7)
    CSWAP(1,2) CSWAP(5,6)
    CSWAP(0,4) CSWAP(1,5) CSWAP(2,6) CSWAP(3,7)
    CSWAP(2,4) CSWAP(3,5)
    CSWAP(1,2) CSWAP(3,4) CSWAP(5,6)

    const int wv = tid >> 6, ln = tid & 63;
    unsigned long long lb = keys[0];

    // level 1: per-wave top-7; only each thread's head competes. Winner is a
    // single lane (bin ids are unique); it shifts its sorted list down.
    for (int it = 0; it < TOPK; ++it) {
        unsigned long long v = lb;
#pragma unroll
        for (int off = 32; off; off >>= 1) {
            unsigned long long o = __shfl_xor(v, off);
            if (o > v) v = o;
        }
        if (ln == 0) wavetop[wv * TOPK + it] = v;
        if (v == lb && v) {
            keys[0]=keys[1]; keys[1]=keys[2]; keys[2]=keys[3]; keys[3]=keys[4];
            keys[4]=keys[5]; keys[5]=keys[6]; keys[6]=keys[7]; keys[7]=0ULL;
            lb = keys[0];
        }
    }
    __syncthreads();

    // level 2: merge 28 candidates on one wave (offs <=16 keep lanes <32)
    if (tid < 32) {
        unsigned long long v = (tid < 4 * TOPK) ? wavetop[tid] : 0ULL;
        for (int it = 0; it < TOPK; ++it) {
            unsigned long long m = v;
#pragma unroll
            for (int off = 16; off; off >>= 1) {
                unsigned long long o = __shfl_xor(m, off);
                if (o > m) m = o;
            }
            if (tid == 0) selkey[it] = m;
            if (m == v) v = 0ULL;
        }
    }
    __syncthreads();

    // emit: out = a*cos(theta)+b*sin(theta), theta = 2*pi*k*n/T
    // a = 4*Re/T, b = -4*Im/T (reference double-counts via explicit conjugates)
    // wr + i*wi = e^{+i*2*pi*k/T} for the recon rotator (tw holds e^{-i...}).
    if (tid < TOPK) {
        int k  = 2047 - (int)(selkey[tid] & 2047ULL);
        float2 ykf = zz[AD(k)];
        float2 ypf = zz[AD(N2 - k)];
        double ykx = (double)ykf.x, yky = (double)ykf.y;
        double ypx = (double)ypf.x, ypy = (double)ypf.y;
        double Ar = 0.5 * (ykx + ypx), Ai = 0.5 * (yky - ypy);
        double Br = 0.5 * (yky + ypy), Bi = -0.5 * (ykx - ypx);
        double2 t = tw[k];
        double Xr = Ar + t.x * Br - t.y * Bi;
        double Xi = Ai + t.x * Bi + t.y * Br;
        k_out[tid * 4096 + bc] = k;
        ab4[tid * 4096 + bc] = make_float4(
            (float)( 4.0 * Xr / (double)T_LEN),
            (float)(-4.0 * Xi / (double)T_LEN),
            (float)t.x, (float)(-t.y));
    }
}

// ---------------- K2: reconstruction via per-frequency rotators --------------
// block = 256 threads (one per channel), grid = 16 b * 64 n-chunks of 64.
// Chunk 64 (was 32) halves the redundant coefficient traffic (73 -> 37 MB)
// and halves per-block setup. Rotators reseeded every 16 steps from the exact
// integer-reduced phase (drift <= 16 ulp, tighter than before).
// Output staged in LDS 16n x 256c subtiles -> contiguous float4 stores.
__global__ __launch_bounds__(256) void recon_kernel(
    const int* __restrict__ k_in, const float4* __restrict__ ab4,
    float* __restrict__ out)
{
    __shared__ float tile[16][256];

    const int tid   = threadIdx.x;        // channel c
    const int chunk = blockIdx.x & 63;
    const int b     = blockIdx.x >> 6;
    const int bc    = (b << 8) + tid;
    const int n0    = chunk << 6;         // 64 time steps per block

    const float c0 = 6.28318530717958647692f / 4096.0f;
    int   kk[TOPK];
    float aa[TOPK], bb[TOPK], zr[TOPK], zi[TOPK], wr[TOPK], wi[TOPK];
#pragma unroll
    for (int j = 0; j < TOPK; ++j) {
        kk[j] = k_in[j * 4096 + bc];
        float4 v = ab4[j * 4096 + bc];
        aa[j] = v.x; bb[j] = v.y; wr[j] = v.z; wi[j] = v.w;
    }

    float* obase = out + ((size_t)b * T_LEN + n0) * NCH;
    for (int sub = 0; sub < 4; ++sub) {       // 4 subtiles of 16 n
        int ns = n0 + (sub << 4);
#pragma unroll
        for (int j = 0; j < TOPK; ++j) {
            int m0 = (kk[j] * ns) & (T_LEN - 1);  // exact integer phase reduction
            float ang = (float)m0 * c0;
            __sincosf(ang, &zi[j], &zr[j]);
        }
#pragma unroll
        for (int i = 0; i < 16; ++i) {
            float acc = 0.f;
#pragma unroll
            for (int j = 0; j < TOPK; ++j) {
                acc += aa[j] * zr[j] + bb[j] * zi[j];
                float nzr = zr[j] * wr[j] - zi[j] * wi[j];
                zi[j] = zr[j] * wi[j] + zi[j] * wr[j];
                zr[j] = nzr;
            }
            tile[i][tid] = acc;
        }
        __syncthreads();
        // 1024 float4s per subtile, 4 per thread, contiguous per wave
#pragma unroll
        for (int s = 0; s < 4; ++s) {
            int fid = tid + (s << 8);
            int ni  = fid >> 6;
            int c4  = (fid & 63) << 2;
            float4 v = make_float4(tile[ni][c4], tile[ni][c4 + 1],
                                   tile[ni][c4 + 2], tile[ni][c4 + 3]);
            *(float4*)(obase + (size_t)((sub << 4) + ni) * NCH + c4) = v;
        }
        __syncthreads();
    }
}

// ---------------- launch -----------------------------------------------------
extern "C" void kernel_launch(void* const* d_in, const int* in_sizes, int n_in,
                              void* d_out, int out_size, void* d_ws, size_t ws_size,
                              hipStream_t stream) {
    const float* x   = (const float*)d_in[0];
    float*       out = (float*)d_out;
    char*        ws  = (char*)d_ws;

    // ws layout: [0, 65536)            tw   double2[4096]
    //            [65536, +114688)      k    int[7][4096]
    //            [180224, +458752)     ab4  float4[7][4096]
    //            [638976, +32768)      twf  float2[4096]
    double2* tw    = (double2*)(ws);
    int*     k_ws  = (int*)   (ws + 65536);
    float4*  ab_ws = (float4*)(ws + 180224);
    float2*  twf   = (float2*)(ws + 638976);

    // d_out doubles as the transposed-x scratch (exactly 64 MB); recon_kernel
    // overwrites every element of it last, so validation sees only the output.
    prep_kernel     <<<16 + 4096, 256, 0, stream>>>(x, out, tw, twf);
    fft_topk_kernel <<<4096, 256, 0, stream>>>(out, tw, twf, k_ws, ab_ws);
    recon_kernel    <<<1024, 256, 0, stream>>>(k_ws, ab_ws, out);
}

// Round 5
// 172.667 us; speedup vs baseline: 1.1383x; 1.0516x over previous
//
#include <hip/hip_runtime.h>
#include <math.h>

#define T_LEN 4096   // time length (FFT size)
#define N2    2048   // packed complex FFT size
#define TOPK  7      // int(ln(2047)) = 7
#define NCH   256    // channels (d)
#define R8F 0.70710678f              // sqrt(2)/2 in f32

// LDS slot map for interleaved complex storage.
// AD(a) = a + (a>>3) + (a>>8): conflict-floor access for every phase pattern
// (strides 256, 32, 4, 1, quad-gather, natural order).
#define AD(a) ((a) + ((a) >> 3) + ((a) >> 8))

// native clang vector type: required by __builtin_nontemporal_load/store
// (HIP_vector_type<float,4>* is rejected — round-4 compile failure).
typedef float nt_f4 __attribute__((ext_vector_type(4)));

// complex f32 helpers structured for v_pk_add_f32 / v_pk_fma_f32 SLP packing:
// re/im ops are elementwise-identical adds/subs wherever possible.
typedef float2 c32;
__device__ __forceinline__ c32 cadd(c32 a, c32 b) { return make_float2(a.x + b.x, a.y + b.y); }
__device__ __forceinline__ c32 csub(c32 a, c32 b) { return make_float2(a.x - b.x, a.y - b.y); }
__device__ __forceinline__ c32 cmul(c32 a, c32 w) {
    return make_float2(w.x * a.x - w.y * a.y, w.x * a.y + w.y * a.x);
}
__device__ __forceinline__ c32 csq(c32 a) {
    return make_float2(a.x * a.x - a.y * a.y, 2.0f * a.x * a.y);
}
__device__ __forceinline__ c32 mulnegi(c32 a) { return make_float2(a.y, -a.x); }  // a * (-i)

// ---------------- K0: fused twiddle tables + transpose -----------------------
// blocks [0,16): tw[p] = e^{-2*pi*i*p/4096} (f64) and twf[p] (f32), p=0..4095
// blocks [16, 16+4096): transpose x (b,t,c) -> xt (b,c,t); xt lives in d_out.
// x is read exactly once -> nontemporal loads keep L2/L3 free for xt.
__global__ __launch_bounds__(256) void prep_kernel(
    const float* __restrict__ x, float* __restrict__ xt,
    double2* __restrict__ tw, float2* __restrict__ twf)
{
    if (blockIdx.x < 16) {
        int p = blockIdx.x * 256 + threadIdx.x;
        double th = -2.0 * 3.14159265358979323846 * (double)p / (double)T_LEN;
        double c = cos(th), s = sin(th);
        tw[p]  = make_double2(c, s);
        twf[p] = make_float2((float)c, (float)s);
        return;
    }
    __shared__ float tile[64][65];
    const int bid = blockIdx.x - 16;
    const int t0  = (bid & 63) * 64;
    const int c0  = ((bid >> 6) & 3) * 64;
    const int b   = bid >> 8;
    const int tx4 = (threadIdx.x & 15) * 4;
    const int ty  = threadIdx.x >> 4;

    const float* src = x + (size_t)b * T_LEN * NCH;
    for (int r = 0; r < 4; ++r) {
        int t = ty + r * 16;
        nt_f4 v = __builtin_nontemporal_load(
            (const nt_f4*)(src + (size_t)(t0 + t) * NCH + c0 + tx4));
        tile[t][tx4 + 0] = v.x; tile[t][tx4 + 1] = v.y;
        tile[t][tx4 + 2] = v.z; tile[t][tx4 + 3] = v.w;
    }
    __syncthreads();
    float* dst = xt + (size_t)b * NCH * T_LEN;
    for (int r = 0; r < 4; ++r) {
        int c = ty + r * 16;
        float4 v = make_float4(tile[tx4 + 0][c], tile[tx4 + 1][c],
                               tile[tx4 + 2][c], tile[tx4 + 3][c]);
        *(float4*)(dst + (size_t)(c0 + c) * T_LEN + t0 + tx4) = v;
    }
}

// DIF radix-8 butterfly on c32 registers. Twiddles generated in-register as
// powers of w1 = e^{-2*pi*i*base/4096} (ONE 8 B load per call instead of 7
// lane-scattered loads). Power error <= ~5 ulp, far below selection gaps.
__device__ __forceinline__ void dft8_pw(c32 x[8], c32 w1)
{
    c32 t0 = cadd(x[0], x[4]), t4 = csub(x[0], x[4]);
    c32 t1 = cadd(x[1], x[5]), t5 = csub(x[1], x[5]);
    c32 t2 = cadd(x[2], x[6]), t6 = csub(x[2], x[6]);
    c32 t3 = cadd(x[3], x[7]), t7 = csub(x[3], x[7]);
    c32 s0 = cadd(t0, t2), s2 = csub(t0, t2);
    c32 s1 = cadd(t1, t3), s3 = csub(t1, t3);
    x[0] = cadd(s0, s1);
    x[4] = csub(s0, s1);
    c32 s3n = mulnegi(s3);
    x[2] = cadd(s2, s3n);                  // s2 - i*s3
    x[6] = csub(s2, s3n);                  // s2 + i*s3
    c32 c1 = make_float2(R8F * (t5.x + t5.y), R8F * (t5.y - t5.x));
    c32 c2 = mulnegi(t6);
    c32 c3 = make_float2(R8F * (t7.y - t7.x), -R8F * (t7.x + t7.y));
    c32 d0 = cadd(t4, c2), d1 = csub(t4, c2);
    c32 d2 = cadd(c1, c3), d3 = csub(c1, c3);
    x[1] = cadd(d0, d2);
    x[5] = csub(d0, d2);
    c32 d3n = mulnegi(d3);
    x[3] = cadd(d1, d3n);                  // d1 - i*d3
    x[7] = csub(d1, d3n);                  // d1 + i*d3

    c32 w2 = csq(w1);
    c32 w3 = cmul(w1, w2);
    c32 w4 = csq(w2);
    c32 w5 = cmul(w3, w2);
    c32 w6 = csq(w3);
    c32 w7 = cmul(w4, w3);
    x[1] = cmul(x[1], w1);
    x[2] = cmul(x[2], w2);
    x[3] = cmul(x[3], w3);
    x[4] = cmul(x[4], w4);
    x[5] = cmul(x[5], w5);
    x[6] = cmul(x[6], w6);
    x[7] = cmul(x[7], w7);
}

// pack (f32 magnitude^2 bits, bin) into one monotone u64 key: higher mag wins;
// exact f32 ties -> lower k wins. mag >= 0 so IEEE bits compare monotonically
// as unsigned. Full f32 precision preserved (no mantissa truncation).
__device__ __forceinline__ unsigned long long packkey32(float mag, int k) {
    return ((unsigned long long)__float_as_uint(mag) << 32)
         | (unsigned long long)(2047 - k);
}

// descending compare-swap for the per-thread sorting network
#define CSWAP(i, j) { unsigned long long a_ = keys[i], b_ = keys[j]; \
                      keys[i] = a_ > b_ ? a_ : b_; keys[j] = a_ > b_ ? b_ : a_; }

// ---------------- K1: register radix-8 real FFT (f32) + top-7 ----------------
// One block per (b,c) column, contiguous in xt. Packed: y_m = x[2m]+i*x[2m+1].
// Top-7: per-thread 8-key sort (Batcher net) -> per-wave rounds with a 32-bit
// max-butterfly on the mag word + ballot winner-resolve (u64 butterfly was
// 2x the instructions); exact-mag ties fall to a rare uniform branch that
// reduces the low word (lower k wins -> identical semantics to u64 compare).
__global__ __launch_bounds__(256, 8) void fft_topk_kernel(
    const float* __restrict__ xt, const double2* __restrict__ tw,
    const float2* __restrict__ twf,
    int* __restrict__ k_out, float4* __restrict__ ab4)
{
    __shared__ float2 zz[AD(N2 - 1) + 3];            // 2312 float2 = 18.5 KB
    __shared__ unsigned long long wavetop[4 * TOPK]; // 28 wave-level candidates
    __shared__ unsigned long long selkey[TOPK];

    const int tid = threadIdx.x;
    const int bc  = blockIdx.x;          // b*256 + c
    const float2* xcol2 = (const float2*)(xt + (size_t)bc * T_LEN);

    c32 x[8];
    // phase 1: load y[tid + 256u] (coalesced float2), radix-8, tw base 2*tid
#pragma unroll
    for (int u = 0; u < 8; ++u)
        x[u] = xcol2[tid + (u << 8)];
    dft8_pw(x, twf[2 * tid]);
#pragma unroll
    for (int m = 0; m < 8; ++m)
        zz[AD((m << 8) + tid)] = x[m];
    __syncthreads();

    // phase 2: sub-FFT size 256, j2 = tid&31, stride 32; tw base 16*j2.
    // Each thread reads and writes ONLY its own 8 slots -> no intra barrier.
    {
        const int g = tid >> 5, j2 = tid & 31, base = (g << 8) + j2;
#pragma unroll
        for (int u = 0; u < 8; ++u)
            x[u] = zz[AD(base + (u << 5))];
        dft8_pw(x, twf[16 * j2]);
#pragma unroll
        for (int m = 0; m < 8; ++m)
            zz[AD(base + (m << 5))] = x[m];
    }
    __syncthreads();

    // phase 3: sub-FFT size 32, j3 = tid&3, stride 4; tw base 128*j3.
    {
        const int g3 = tid >> 2, j3 = tid & 3, base = (g3 << 5) + j3;
#pragma unroll
        for (int u = 0; u < 8; ++u)
            x[u] = zz[AD(base + (u << 2))];
        dft8_pw(x, twf[128 * j3]);
#pragma unroll
        for (int m = 0; m < 8; ++m)
            zz[AD(base + (m << 2))] = x[m];
    }
    __syncthreads();

    // phase 4: read both stride-1 quads into registers (digit-index space),
    // barrier, DFT4 in registers, write natural-order at AD(k).
#pragma unroll
    for (int q = 0; q < 2; ++q) {
        int h4 = ((q << 8) + tid) << 2;
#pragma unroll
        for (int r = 0; r < 4; ++r)
            x[q * 4 + r] = zz[AD(h4 + r)];
    }
    __syncthreads();
#pragma unroll
    for (int q = 0; q < 2; ++q) {
        c32 b0 = x[q*4+0], b1 = x[q*4+1], b2 = x[q*4+2], b3 = x[q*4+3];
        c32 e0 = cadd(b0, b2), e1 = csub(b0, b2);
        c32 e2 = cadd(b1, b3), e3 = csub(b1, b3);
        c32 e3n = mulnegi(e3);
        // position p = 4*(q*256+tid)+r  <->  bin k = kbase + r*512
        int kbase = ((tid & 7) << 6) | (((tid >> 3) & 7) << 3) | (q << 2) | (tid >> 6);
        zz[AD(kbase)]        = cadd(e0, e2);
        zz[AD(kbase + 1024)] = csub(e0, e2);
        zz[AD(kbase +  512)] = cadd(e1, e3n);   // e1 - i*e3
        zz[AD(kbase + 1536)] = csub(e1, e3n);   // e1 + i*e3
    }
    __syncthreads();

    // conjugate-pair magnitudes: k in [1,1024]; |X[k]|^2 = |A+WB|^2,
    // |X[2048-k]|^2 = |A-WB|^2 from ONE read pair (Y[k], Y[2048-k]).
    unsigned long long keys[8];
#pragma unroll
    for (int j = 0; j < 4; ++j) {
        int k  = 1 + tid + (j << 8);      // 1..1024
        int kp = N2 - k;                  // 1024..2047
        float2 yk = zz[AD(k)];
        float2 yp = zz[AD(kp)];
        float Ar = 0.5f * (yk.x + yp.x), Ai = 0.5f * (yk.y - yp.y);
        float Br = 0.5f * (yk.y + yp.y), Bi = -0.5f * (yk.x - yp.x);
        float2 t = twf[k];                // lane-stride 8 B: coalesced
        float Cr = t.x * Br - t.y * Bi;
        float Ci = t.x * Bi + t.y * Br;
        float m1 = (Ar + Cr) * (Ar + Cr) + (Ai + Ci) * (Ai + Ci);
        float m2 = (Ar - Cr) * (Ar - Cr) + (Ai - Ci) * (Ai - Ci);
        keys[2 * j]     = packkey32(m1, k);
        keys[2 * j + 1] = (kp != k) ? packkey32(m2, kp) : 0ULL;
    }

    // ---- per-thread descending sort (Batcher 8-element network, 19 CEs)
    CSWAP(0,1) CSWAP(2,3) CSWAP(4,5) CSWAP(6,7)
    CSWAP(0,2) CSWAP(1,3) CSWAP(4,6) CSWAP(5,7)
    CSWAP(1,2) CSWAP(5,6)
    CSWAP(0,4) CSWAP(1,5) CSWAP(2,6) CSWAP(3,7)
    CSWAP(2,4) CSWAP(3,5)
    CSWAP(1,2) CSWAP(3,4) CSWAP(5,6)

    const int wv = tid >> 6, ln = tid & 63;
    unsigned long long lb = keys[0];

    // level 1: per-wave top-7; only each thread's head competes. Winner is a
    // single lane (bin ids are unique); it shifts its sorted list down.
    for (int it = 0; it < TOPK; ++it) {
        unsigned int hl = (unsigned int)(lb >> 32);
        unsigned int h  = hl;
#pragma unroll
        for (int off = 32; off; off >>= 1) {
            unsigned int o = __shfl_xor(h, off);
            h = (o > h) ? o : h;
        }
        unsigned long long mask = __ballot(hl == h);
        unsigned long long v;
        if (__popcll(mask) == 1) {
            int src = __ffsll((long long)mask) - 1;
            v = ((unsigned long long)h << 32)
              | (unsigned long long)__shfl((unsigned int)lb, src);
        } else {
            // exact f32-mag tie across lanes: max low word = lower k wins
            unsigned int l = (hl == h) ? (unsigned int)lb : 0u;
#pragma unroll
            for (int off = 32; off; off >>= 1) {
                unsigned int o = __shfl_xor(l, off);
                l = (o > l) ? o : l;
            }
            v = ((unsigned long long)h << 32) | l;
        }
        if (ln == 0) wavetop[wv * TOPK + it] = v;
        if (v == lb && v) {
            keys[0]=keys[1]; keys[1]=keys[2]; keys[2]=keys[3]; keys[3]=keys[4];
            keys[4]=keys[5]; keys[5]=keys[6]; keys[6]=keys[7]; keys[7]=0ULL;
            lb = keys[0];
        }
    }
    __syncthreads();

    // level 2: merge 28 candidates on one wave (offs <=16 keep lanes <32)
    if (tid < 32) {
        unsigned long long v = (tid < 4 * TOPK) ? wavetop[tid] : 0ULL;
        for (int it = 0; it < TOPK; ++it) {
            unsigned long long m = v;
#pragma unroll
            for (int off = 16; off; off >>= 1) {
                unsigned long long o = __shfl_xor(m, off);
                if (o > m) m = o;
            }
            if (tid == 0) selkey[it] = m;
            if (m == v) v = 0ULL;
        }
    }
    __syncthreads();

    // emit: out = a*cos(theta)+b*sin(theta), theta = 2*pi*k*n/T
    // a = 4*Re/T, b = -4*Im/T (reference double-counts via explicit conjugates)
    // wr + i*wi = e^{+i*2*pi*k/T} for the recon rotator (tw holds e^{-i...}).
    if (tid < TOPK) {
        int k  = 2047 - (int)(selkey[tid] & 2047ULL);
        float2 ykf = zz[AD(k)];
        float2 ypf = zz[AD(N2 - k)];
        double ykx = (double)ykf.x, yky = (double)ykf.y;
        double ypx = (double)ypf.x, ypy = (double)ypf.y;
        double Ar = 0.5 * (ykx + ypx), Ai = 0.5 * (yky - ypy);
        double Br = 0.5 * (yky + ypy), Bi = -0.5 * (ykx - ypx);
        double2 t = tw[k];
        double Xr = Ar + t.x * Br - t.y * Bi;
        double Xi = Ai + t.x * Bi + t.y * Br;
        k_out[tid * 4096 + bc] = k;
        ab4[tid * 4096 + bc] = make_float4(
            (float)( 4.0 * Xr / (double)T_LEN),
            (float)(-4.0 * Xi / (double)T_LEN),
            (float)t.x, (float)(-t.y));
    }
}

// ---------------- K2: reconstruction via per-frequency rotators --------------
// block = 256 threads (one per channel), grid = 16 b * 128 n-chunks of 32.
// (chunk-64 variant regressed: coefficients are L2-resident so the re-reads
// were free; bigger chunks just added reseeds and halved latency hiding.)
// Output staged in LDS 16n x 256c subtiles -> contiguous nontemporal float4.
__global__ __launch_bounds__(256) void recon_kernel(
    const int* __restrict__ k_in, const float4* __restrict__ ab4,
    float* __restrict__ out)
{
    __shared__ float tile[16][256];

    const int tid   = threadIdx.x;        // channel c
    const int chunk = blockIdx.x & 127;
    const int b     = blockIdx.x >> 7;
    const int bc    = (b << 8) + tid;
    const int n0    = chunk << 5;         // 32 time steps per block

    const float c0 = 6.28318530717958647692f / 4096.0f;
    float aa[TOPK], bb[TOPK];
    c32 z[TOPK], w[TOPK];
#pragma unroll
    for (int j = 0; j < TOPK; ++j) {
        int k    = k_in[j * 4096 + bc];
        float4 v = ab4[j * 4096 + bc];
        aa[j] = v.x; bb[j] = v.y; w[j] = make_float2(v.z, v.w);
        int m0 = (k * n0) & (T_LEN - 1);      // exact integer phase reduction
        float ang = (float)m0 * c0;
        __sincosf(ang, &z[j].y, &z[j].x);
    }

    float* obase = out + ((size_t)b * T_LEN + n0) * NCH;
    for (int r = 0; r < 2; ++r) {             // 2 subtiles of 16 n
#pragma unroll
        for (int i = 0; i < 16; ++i) {
            float acc = 0.f;
#pragma unroll
            for (int j = 0; j < TOPK; ++j) {
                acc += aa[j] * z[j].x + bb[j] * z[j].y;
                z[j] = cmul(z[j], w[j]);
            }
            tile[i][tid] = acc;
        }
        __syncthreads();
        // 1024 float4s per subtile, 4 per thread, contiguous per wave
#pragma unroll
        for (int s = 0; s < 4; ++s) {
            int fid = tid + (s << 8);
            int ni  = fid >> 6;
            int c4  = (fid & 63) << 2;
            nt_f4 v = { tile[ni][c4], tile[ni][c4 + 1],
                        tile[ni][c4 + 2], tile[ni][c4 + 3] };
            __builtin_nontemporal_store(v,
                (nt_f4*)(obase + (size_t)((r << 4) + ni) * NCH + c4));
        }
        __syncthreads();
    }
}

// ---------------- launch -----------------------------------------------------
extern "C" void kernel_launch(void* const* d_in, const int* in_sizes, int n_in,
                              void* d_out, int out_size, void* d_ws, size_t ws_size,
                              hipStream_t stream) {
    const float* x   = (const float*)d_in[0];
    float*       out = (float*)d_out;
    char*        ws  = (char*)d_ws;

    // ws layout: [0, 65536)            tw   double2[4096]
    //            [65536, +114688)      k    int[7][4096]
    //            [180224, +458752)     ab4  float4[7][4096]
    //            [638976, +32768)      twf  float2[4096]
    double2* tw    = (double2*)(ws);
    int*     k_ws  = (int*)   (ws + 65536);
    float4*  ab_ws = (float4*)(ws + 180224);
    float2*  twf   = (float2*)(ws + 638976);

    // d_out doubles as the transposed-x scratch (exactly 64 MB); recon_kernel
    // overwrites every element of it last, so validation sees only the output.
    prep_kernel     <<<16 + 4096, 256, 0, stream>>>(x, out, tw, twf);
    fft_topk_kernel <<<4096, 256, 0, stream>>>(out, tw, twf, k_ws, ab_ws);
    recon_kernel    <<<2048, 256, 0, stream>>>(k_ws, ab_ws, out);
}